// Round 1
// baseline (660.914 us; speedup 1.0000x reference)
//
#include <hip/hip_runtime.h>

typedef unsigned short u16;
typedef unsigned int u32;
typedef short s8v __attribute__((ext_vector_type(8)));
typedef float f4v __attribute__((ext_vector_type(4)));

__device__ __forceinline__ u16 f2bf(float f) {
  u32 u = __builtin_bit_cast(u32, f);
  u32 r = (u + 0x7FFFu + ((u >> 16) & 1u)) >> 16;
  return (u16)r;
}
__device__ __forceinline__ float bf2f(u16 h) {
  u32 u = ((u32)h) << 16;
  return __builtin_bit_cast(float, u);
}

// ---------------- f32 -> bf16 convert (vectorized) ----------------
__global__ __launch_bounds__(256) void cvt_f32_bf16(const float* __restrict__ in,
                                                    u16* __restrict__ out, int n4) {
  int i = blockIdx.x * 256 + threadIdx.x;
  if (i >= n4) return;
  float4 v = reinterpret_cast<const float4*>(in)[i];
  u16 o0 = f2bf(v.x), o1 = f2bf(v.y), o2 = f2bf(v.z), o3 = f2bf(v.w);
  reinterpret_cast<uint2*>(out)[i] =
      make_uint2(o0 | ((u32)o1 << 16), o2 | ((u32)o3 << 16));
}

// ---------------- prep: build xh in both layouts ----------------
// gt0[c = b*160+f][n]  (bf16, transposed, ld 4096)
// grows[(n*16+b)][f]   (bf16, row layout, ld 480), f in [0,160)
__global__ __launch_bounds__(256) void prep_kernel(const float* __restrict__ x_t,
                                                   const float* __restrict__ h_prev,
                                                   u16* __restrict__ gt0,
                                                   u16* __restrict__ grows) {
  __shared__ u16 T[160][72];
  const int t = threadIdx.x;
  const int n0 = blockIdx.x * 64;
  const int b = blockIdx.y;
  // x part: 64n x 32f
#pragma unroll
  for (int q = 0; q < 2; ++q) {
    int idx = t + q * 256;
    int n_loc = idx >> 3, f = (idx & 7) << 2;
    int n = n0 + n_loc;
    float4 v = *reinterpret_cast<const float4*>(&x_t[((size_t)b * 4096 + n) * 32 + f]);
    u16 o[4] = {f2bf(v.x), f2bf(v.y), f2bf(v.z), f2bf(v.w)};
    *reinterpret_cast<uint2*>(&grows[((size_t)n * 16 + b) * 480 + f]) =
        make_uint2(o[0] | ((u32)o[1] << 16), o[2] | ((u32)o[3] << 16));
#pragma unroll
    for (int i = 0; i < 4; ++i) T[f + i][n_loc] = o[i];
  }
  // h part: 64n x 128f
#pragma unroll
  for (int q = 0; q < 8; ++q) {
    int idx = t + q * 256;
    int n_loc = idx >> 5, f = (idx & 31) << 2;
    int n = n0 + n_loc;
    float4 v = *reinterpret_cast<const float4*>(&h_prev[((size_t)b * 4096 + n) * 128 + f]);
    u16 o[4] = {f2bf(v.x), f2bf(v.y), f2bf(v.z), f2bf(v.w)};
    *reinterpret_cast<uint2*>(&grows[((size_t)n * 16 + b) * 480 + 32 + f]) =
        make_uint2(o[0] | ((u32)o[1] << 16), o[2] | ((u32)o[3] << 16));
#pragma unroll
    for (int i = 0; i < 4; ++i) T[32 + f + i][n_loc] = o[i];
  }
  __syncthreads();
  if (t < 160) {
    u16* dst = &gt0[((size_t)b * 160 + t) * 4096 + n0];
    const u16* src = &T[t][0];
#pragma unroll
    for (int q = 0; q < 8; ++q)
      reinterpret_cast<uint4*>(dst)[q] = *reinterpret_cast<const uint4*>(src + q * 8);
  }
}

// ---------------- NT GEMM: out[m][c] = sum_k A[m][k]*Bt[c][k] ----------------
// MODE 0: mix. out0 = gt_next (bf16 [c][m], ld 4096); out1 = grows+choff (ld 480)
// MODE 1: z/r gates. col<128 -> sigmoid+bias0 -> out0 ; else sigmoid+bias1 -> out1 (ld 128)
// MODE 2: h gate. tanh+bias0 -> out0 (ld 128)
template <int MODE>
__global__ __launch_bounds__(256, 2) void gemm_nt(const u16* __restrict__ A, int lda,
                                                  const u16* __restrict__ Bt, int ldb,
                                                  int K, u16* __restrict__ out0,
                                                  u16* __restrict__ out1,
                                                  const float* __restrict__ bias0,
                                                  const float* __restrict__ bias1) {
  constexpr int BK = 32, LDP = 40;
  __shared__ u16 As[128 * LDP];
  __shared__ u16 Bs[128 * LDP];
  const int tid = threadIdx.x;
  const int lane = tid & 63, wid = tid >> 6;
  const int wr = wid >> 1, wc = wid & 1;
  const int bm0 = blockIdx.x * 128, bn0 = blockIdx.y * 128;
  f4v acc[4][4];
#pragma unroll
  for (int i = 0; i < 4; ++i)
#pragma unroll
    for (int j = 0; j < 4; ++j) acc[i][j] = (f4v){0.f, 0.f, 0.f, 0.f};

  const int rsel = lane & 15, ksel = (lane >> 4) << 3;
  for (int k0 = 0; k0 < K; k0 += BK) {
#pragma unroll
    for (int c = 0; c < 2; ++c) {
      int chunk = tid + c * 256;
      int row = chunk >> 2, kc = (chunk & 3) << 3;
      *reinterpret_cast<uint4*>(&As[row * LDP + kc]) =
          *reinterpret_cast<const uint4*>(&A[(size_t)(bm0 + row) * lda + k0 + kc]);
      *reinterpret_cast<uint4*>(&Bs[row * LDP + kc]) =
          *reinterpret_cast<const uint4*>(&Bt[(size_t)(bn0 + row) * ldb + k0 + kc]);
    }
    __syncthreads();
    s8v af[4], bfr[4];
#pragma unroll
    for (int i = 0; i < 4; ++i) {
      af[i] = *reinterpret_cast<const s8v*>(&As[(wr * 64 + i * 16 + rsel) * LDP + ksel]);
      bfr[i] = *reinterpret_cast<const s8v*>(&Bs[(wc * 64 + i * 16 + rsel) * LDP + ksel]);
    }
#pragma unroll
    for (int i = 0; i < 4; ++i)
#pragma unroll
      for (int j = 0; j < 4; ++j)
        acc[i][j] = __builtin_amdgcn_mfma_f32_16x16x32_bf16(af[i], bfr[j], acc[i][j], 0, 0, 0);
    __syncthreads();
  }

  const int mbase = bm0 + wr * 64 + ((lane >> 4) << 2);
  const int cbase = bn0 + wc * 64 + (lane & 15);
  if (MODE == 0) {
#pragma unroll
    for (int j = 0; j < 4; ++j) {
      int c = cbase + j * 16;
      int cb = c / 160;
      int cf = c - cb * 160;
#pragma unroll
      for (int i = 0; i < 4; ++i) {
        int m = mbase + i * 16;
        u16 o[4];
#pragma unroll
        for (int r = 0; r < 4; ++r) o[r] = f2bf(acc[i][j][r]);
        *reinterpret_cast<uint2*>(&out0[(size_t)c * 4096 + m]) =
            make_uint2(o[0] | ((u32)o[1] << 16), o[2] | ((u32)o[3] << 16));
#pragma unroll
        for (int r = 0; r < 4; ++r)
          out1[((size_t)(m + r) * 16 + cb) * 480 + cf] = o[r];
      }
    }
  } else {
#pragma unroll
    for (int j = 0; j < 4; ++j) {
      int c = cbase + j * 16;
      bool primary = (MODE == 2) || (c < 128);
      int cc = primary ? c : c - 128;
      float bv = primary ? bias0[cc] : bias1[cc];
      u16* dst = primary ? out0 : out1;
#pragma unroll
      for (int i = 0; i < 4; ++i) {
#pragma unroll
        for (int r = 0; r < 4; ++r) {
          float x = acc[i][j][r] + bv;
          float v = (MODE == 1) ? (1.f / (1.f + __expf(-x))) : tanhf(x);
          dst[(size_t)(mbase + i * 16 + r) * 128 + cc] = f2bf(v);
        }
      }
    }
  }
}

// ---------------- cand: multiply h-features by r in both layouts ----------------
__global__ __launch_bounds__(256) void cand_kernel(u16* __restrict__ grows,
                                                   u16* __restrict__ gt0,
                                                   const u16* __restrict__ rbuf) {
  const int t = threadIdx.x;
  const int n0 = blockIdx.x * 64;
  const int b = blockIdx.y;
  // grows rows: grows[(n*16+b)][32+d] *= r[(n*16+b)][d]
  {
    int n = n0 + (t >> 2);
    int d0 = (t & 3) << 5;
    size_t row = (size_t)n * 16 + b;
#pragma unroll
    for (int q = 0; q < 4; ++q) {
      int d = d0 + q * 8;
      uint4 rv = *reinterpret_cast<const uint4*>(&rbuf[row * 128 + d]);
      uint4 gv = *reinterpret_cast<const uint4*>(&grows[row * 480 + 32 + d]);
      const u16* rp = reinterpret_cast<const u16*>(&rv);
      const u16* gp = reinterpret_cast<const u16*>(&gv);
      uint4 ov;
      u16* op = reinterpret_cast<u16*>(&ov);
#pragma unroll
      for (int i = 0; i < 8; ++i) op[i] = f2bf(bf2f(gp[i]) * bf2f(rp[i]));
      *reinterpret_cast<uint4*>(&grows[row * 480 + 32 + d]) = ov;
    }
  }
  // gt0 rows: gt0[b*160+32+d][n] *= r[(n*16+b)][d]
  {
    int d = t >> 1;
    int nh = (t & 1) << 5;
    size_t crow = (size_t)b * 160 + 32 + d;
#pragma unroll
    for (int q = 0; q < 4; ++q) {
      int nn = n0 + nh + q * 8;
      uint4 gv = *reinterpret_cast<const uint4*>(&gt0[crow * 4096 + nn]);
      const u16* gp = reinterpret_cast<const u16*>(&gv);
      uint4 ov;
      u16* op = reinterpret_cast<u16*>(&ov);
#pragma unroll
      for (int i = 0; i < 8; ++i) {
        float rv = bf2f(rbuf[((size_t)(nn + i) * 16 + b) * 128 + d]);
        op[i] = f2bf(bf2f(gp[i]) * rv);
      }
      *reinterpret_cast<uint4*>(&gt0[crow * 4096 + nn]) = ov;
    }
  }
}

// ---------------- final: GRU combine + LayerNorm ----------------
__global__ __launch_bounds__(256) void final_kernel(const u16* __restrict__ ht,
                                                    const u16* __restrict__ zbuf,
                                                    const float* __restrict__ h_prev,
                                                    const float* __restrict__ gamma,
                                                    const float* __restrict__ beta,
                                                    float* __restrict__ out) {
  const int lane = threadIdx.x & 63, wid = threadIdx.x >> 6;
  const size_t row = (size_t)blockIdx.x * 4 + wid;  // n*16+b
  const int b = (int)(row & 15), n = (int)(row >> 4);
  const int d0 = lane * 2;
  u32 hv = *reinterpret_cast<const u32*>(&ht[row * 128 + d0]);
  u32 zv = *reinterpret_cast<const u32*>(&zbuf[row * 128 + d0]);
  float2 hp = *reinterpret_cast<const float2*>(&h_prev[((size_t)b * 4096 + n) * 128 + d0]);
  float z0 = bf2f((u16)(zv & 0xFFFF)), z1 = bf2f((u16)(zv >> 16));
  float t0 = bf2f((u16)(hv & 0xFFFF)), t1 = bf2f((u16)(hv >> 16));
  float h0 = (1.f - z0) * hp.x + z0 * t0;
  float h1 = (1.f - z1) * hp.y + z1 * t1;
  float s = h0 + h1, ss = h0 * h0 + h1 * h1;
#pragma unroll
  for (int off = 32; off >= 1; off >>= 1) {
    s += __shfl_xor(s, off);
    ss += __shfl_xor(ss, off);
  }
  float mu = s * (1.f / 128.f);
  float var = ss * (1.f / 128.f) - mu * mu;
  float rstd = rsqrtf(var + 1e-5f);
  float2 gv = *reinterpret_cast<const float2*>(&gamma[d0]);
  float2 bv = *reinterpret_cast<const float2*>(&beta[d0]);
  float o0 = (h0 - mu) * rstd * gv.x + bv.x;
  float o1 = (h1 - mu) * rstd * gv.y + bv.y;
  *reinterpret_cast<float2*>(&out[((size_t)b * 4096 + n) * 128 + d0]) =
      make_float2(o0, o1);
}

extern "C" void kernel_launch(void* const* d_in, const int* in_sizes, int n_in,
                              void* d_out, int out_size, void* d_ws, size_t ws_size,
                              hipStream_t stream) {
  const float* x_t = (const float*)d_in[0];
  const float* h_prev = (const float*)d_in[1];
  const float* adj = (const float*)d_in[2];
  const float* Wz = (const float*)d_in[3];
  const float* bz = (const float*)d_in[4];
  const float* Wr = (const float*)d_in[5];
  const float* br = (const float*)d_in[6];
  const float* Wh = (const float*)d_in[7];
  const float* bh = (const float*)d_in[8];
  const float* gamma = (const float*)d_in[9];
  const float* beta = (const float*)d_in[10];
  float* out = (float*)d_out;

  if (ws_size < (size_t)210083840) return;  // need ~210 MB scratch

  char* ws = (char*)d_ws;
  u16* adjb = (u16*)(ws);                                // 33,554,432 B
  u16* gt0 = (u16*)(ws + 33554432);                      // 3 x 20,971,520 B
  u16* gt1 = gt0 + (size_t)2560 * 4096;
  u16* gt2 = gt1 + (size_t)2560 * 4096;
  u16* grows = (u16*)(ws + 96468992);                    // 62,914,560 B
  u16* zbuf = (u16*)(ws + 159383552);                    // 16,777,216 B
  u16* rbuf = (u16*)(ws + 176160768);                    // 16,777,216 B
  u16* htb = (u16*)(ws + 192937984);                     // 16,777,216 B
  u16* wzr = (u16*)(ws + 209715200);                     // 245,760 B
  u16* whb = (u16*)(ws + 209960960);                     // 122,880 B

  dim3 blk(256);
  // converts
  cvt_f32_bf16<<<dim3(4096), blk, 0, stream>>>(adj, adjb, 4194304);
  cvt_f32_bf16<<<dim3(60), blk, 0, stream>>>(Wz, wzr, 15360);
  cvt_f32_bf16<<<dim3(60), blk, 0, stream>>>(Wr, wzr + 61440, 15360);
  cvt_f32_bf16<<<dim3(60), blk, 0, stream>>>(Wh, whb, 15360);
  // xh in both layouts
  prep_kernel<<<dim3(64, 16), blk, 0, stream>>>(x_t, h_prev, gt0, grows);
  // phase 1 diffusion: g1, g2
  gemm_nt<0><<<dim3(32, 20), blk, 0, stream>>>(adjb, 4096, gt0, 4096, 4096, gt1,
                                               grows + 160, nullptr, nullptr);
  gemm_nt<0><<<dim3(32, 20), blk, 0, stream>>>(adjb, 4096, gt1, 4096, 4096, gt2,
                                               grows + 320, nullptr, nullptr);
  // z, r gates
  gemm_nt<1><<<dim3(512, 2), blk, 0, stream>>>(grows, 480, wzr, 480, 480, zbuf, rbuf,
                                               bz, br);
  // cand: multiply h-features by r (both layouts)
  cand_kernel<<<dim3(64, 16), blk, 0, stream>>>(grows, gt0, rbuf);
  // phase 2 diffusion
  gemm_nt<0><<<dim3(32, 20), blk, 0, stream>>>(adjb, 4096, gt0, 4096, 4096, gt1,
                                               grows + 160, nullptr, nullptr);
  gemm_nt<0><<<dim3(32, 20), blk, 0, stream>>>(adjb, 4096, gt1, 4096, 4096, gt2,
                                               grows + 320, nullptr, nullptr);
  // h_tilde
  gemm_nt<2><<<dim3(512, 1), blk, 0, stream>>>(grows, 480, whb, 480, 480, htb, nullptr,
                                               bh, nullptr);
  // combine + layernorm
  final_kernel<<<dim3(16384), blk, 0, stream>>>(htb, zbuf, h_prev, gamma, beta, out);
}

// Round 2
// 584.766 us; speedup vs baseline: 1.1302x; 1.1302x over previous
//
#include <hip/hip_runtime.h>

typedef unsigned short u16;
typedef unsigned int u32;
typedef short s8v __attribute__((ext_vector_type(8)));
typedef float f4v __attribute__((ext_vector_type(4)));

__device__ __forceinline__ u16 f2bf(float f) {
  u32 u = __builtin_bit_cast(u32, f);
  u32 r = (u + 0x7FFFu + ((u >> 16) & 1u)) >> 16;
  return (u16)r;
}
__device__ __forceinline__ float bf2f(u16 h) {
  u32 u = ((u32)h) << 16;
  return __builtin_bit_cast(float, u);
}

// async global->LDS, 16B per lane; LDS dest is wave-uniform base + lane*16
__device__ __forceinline__ void gload16(const u16* g, u16* l) {
  __builtin_amdgcn_global_load_lds(
      (const __attribute__((address_space(1))) void*)g,
      (__attribute__((address_space(3))) void*)l, 16, 0, 0);
}

// ---------------- f32 -> bf16 convert (vectorized) ----------------
__global__ __launch_bounds__(256) void cvt_f32_bf16(const float* __restrict__ in,
                                                    u16* __restrict__ out, int n4) {
  int i = blockIdx.x * 256 + threadIdx.x;
  if (i >= n4) return;
  float4 v = reinterpret_cast<const float4*>(in)[i];
  u16 o0 = f2bf(v.x), o1 = f2bf(v.y), o2 = f2bf(v.z), o3 = f2bf(v.w);
  reinterpret_cast<uint2*>(out)[i] =
      make_uint2(o0 | ((u32)o1 << 16), o2 | ((u32)o3 << 16));
}

// ---------------- prep: build xh in both layouts ----------------
__global__ __launch_bounds__(256) void prep_kernel(const float* __restrict__ x_t,
                                                   const float* __restrict__ h_prev,
                                                   u16* __restrict__ gt0,
                                                   u16* __restrict__ grows) {
  __shared__ u16 T[160][72];
  const int t = threadIdx.x;
  const int n0 = blockIdx.x * 64;
  const int b = blockIdx.y;
#pragma unroll
  for (int q = 0; q < 2; ++q) {
    int idx = t + q * 256;
    int n_loc = idx >> 3, f = (idx & 7) << 2;
    int n = n0 + n_loc;
    float4 v = *reinterpret_cast<const float4*>(&x_t[((size_t)b * 4096 + n) * 32 + f]);
    u16 o[4] = {f2bf(v.x), f2bf(v.y), f2bf(v.z), f2bf(v.w)};
    *reinterpret_cast<uint2*>(&grows[((size_t)n * 16 + b) * 480 + f]) =
        make_uint2(o[0] | ((u32)o[1] << 16), o[2] | ((u32)o[3] << 16));
#pragma unroll
    for (int i = 0; i < 4; ++i) T[f + i][n_loc] = o[i];
  }
#pragma unroll
  for (int q = 0; q < 8; ++q) {
    int idx = t + q * 256;
    int n_loc = idx >> 5, f = (idx & 31) << 2;
    int n = n0 + n_loc;
    float4 v = *reinterpret_cast<const float4*>(&h_prev[((size_t)b * 4096 + n) * 128 + f]);
    u16 o[4] = {f2bf(v.x), f2bf(v.y), f2bf(v.z), f2bf(v.w)};
    *reinterpret_cast<uint2*>(&grows[((size_t)n * 16 + b) * 480 + 32 + f]) =
        make_uint2(o[0] | ((u32)o[1] << 16), o[2] | ((u32)o[3] << 16));
#pragma unroll
    for (int i = 0; i < 4; ++i) T[32 + f + i][n_loc] = o[i];
  }
  __syncthreads();
  if (t < 160) {
    u16* dst = &gt0[((size_t)b * 160 + t) * 4096 + n0];
    const u16* src = &T[t][0];
#pragma unroll
    for (int q = 0; q < 8; ++q)
      reinterpret_cast<uint4*>(dst)[q] = *reinterpret_cast<const uint4*>(src + q * 8);
  }
}

// ---------------- NT GEMM (m97 structure): out[m][c] = sum_k A[m][k]*Bt[c][k] ----
// MODE 0: mix. out0 = gt_next (bf16 [c][m], ld 4096, skipped if !WT);
//         out1 = grows+off (ld 480). CAND=1: cols are per-batch h-channels only.
// MODE 1: z/r gates. c<128 -> sigmoid+bias0 -> out0 ; else sigmoid+bias1 -> out1
// MODE 2: h gate. tanh+bias0 -> out0
template <int MODE, int CAND, int WT>
__global__ __launch_bounds__(256) void gemm_nt(const u16* __restrict__ A, int lda,
                                               const u16* __restrict__ Bt, int ldb,
                                               int K, u16* __restrict__ out0,
                                               u16* __restrict__ out1,
                                               const float* __restrict__ bias0,
                                               const float* __restrict__ bias1) {
  __shared__ u16 As[128 * 32];
  __shared__ u16 Bs[128 * 32];
  const int tid = threadIdx.x;
  const int lane = tid & 63, wid = tid >> 6;
  const int wr = wid >> 1, wc = wid & 1;
  const int bm0 = blockIdx.x * 128;
  const int bn0 = CAND ? (blockIdx.y * 160 + 32) : (blockIdx.y * 128);

  // staging addresses: wave `wid` covers rows [wid*32, wid*32+32), 2 issues of 16 rows
  const int srow = wid * 32 + (lane >> 2);
  const int skcol = (lane & 3) * 8;
  const u16* aptr = &A[(size_t)(bm0 + srow) * lda + skcol];
  const u16* bptr = &Bt[(size_t)(bn0 + srow) * ldb + skcol];

  f4v acc[4][4];
#pragma unroll
  for (int i = 0; i < 4; ++i)
#pragma unroll
    for (int j = 0; j < 4; ++j) acc[i][j] = (f4v){0.f, 0.f, 0.f, 0.f};

  const int rsel = lane & 15, ksel = (lane >> 4) << 3;
  for (int k0 = 0; k0 < K; k0 += 32) {
#pragma unroll
    for (int q = 0; q < 2; ++q) {
      gload16(aptr + (size_t)q * 16 * lda + k0, &As[wid * 1024 + q * 512]);
      gload16(bptr + (size_t)q * 16 * ldb + k0, &Bs[wid * 1024 + q * 512]);
    }
    __syncthreads();
    s8v af[4], bfr[4];
#pragma unroll
    for (int i = 0; i < 4; ++i) {
      af[i] = *reinterpret_cast<const s8v*>(&As[(wr * 64 + i * 16 + rsel) * 32 + ksel]);
      bfr[i] = *reinterpret_cast<const s8v*>(&Bs[(wc * 64 + i * 16 + rsel) * 32 + ksel]);
    }
#pragma unroll
    for (int i = 0; i < 4; ++i)
#pragma unroll
      for (int j = 0; j < 4; ++j)
        acc[i][j] = __builtin_amdgcn_mfma_f32_16x16x32_bf16(af[i], bfr[j], acc[i][j], 0, 0, 0);
    __syncthreads();
  }

  const int mbase = bm0 + wr * 64 + ((lane >> 4) << 2);
  const int cbase = bn0 + wc * 64 + (lane & 15);
  if (MODE == 0) {
#pragma unroll
    for (int j = 0; j < 4; ++j) {
      int c = cbase + j * 16;
      int cb = c / 160;
      int cf = c - cb * 160;
#pragma unroll
      for (int i = 0; i < 4; ++i) {
        int m = mbase + i * 16;
        u16 o[4];
#pragma unroll
        for (int r = 0; r < 4; ++r) o[r] = f2bf(acc[i][j][r]);
        if (WT)
          *reinterpret_cast<uint2*>(&out0[(size_t)c * 4096 + m]) =
              make_uint2(o[0] | ((u32)o[1] << 16), o[2] | ((u32)o[3] << 16));
#pragma unroll
        for (int r = 0; r < 4; ++r)
          out1[((size_t)(m + r) * 16 + cb) * 480 + cf] = o[r];
      }
    }
  } else {
#pragma unroll
    for (int j = 0; j < 4; ++j) {
      int c = cbase + j * 16;
      bool primary = (MODE == 2) || (c < 128);
      int cc = primary ? c : c - 128;
      float bv = primary ? bias0[cc] : bias1[cc];
      u16* dst = primary ? out0 : out1;
#pragma unroll
      for (int i = 0; i < 4; ++i) {
#pragma unroll
        for (int r = 0; r < 4; ++r) {
          float x = acc[i][j][r] + bv;
          float v = (MODE == 1) ? (1.f / (1.f + __expf(-x))) : tanhf(x);
          dst[(size_t)(mbase + i * 16 + r) * 128 + cc] = f2bf(v);
        }
      }
    }
  }
}

// ---------------- cand: multiply h-features by r in both layouts ----------------
__global__ __launch_bounds__(256) void cand_kernel(u16* __restrict__ grows,
                                                   u16* __restrict__ gt0,
                                                   const u16* __restrict__ rbuf) {
  const int t = threadIdx.x;
  const int n0 = blockIdx.x * 64;
  const int b = blockIdx.y;
  {
    int n = n0 + (t >> 2);
    int d0 = (t & 3) << 5;
    size_t row = (size_t)n * 16 + b;
#pragma unroll
    for (int q = 0; q < 4; ++q) {
      int d = d0 + q * 8;
      uint4 rv = *reinterpret_cast<const uint4*>(&rbuf[row * 128 + d]);
      uint4 gv = *reinterpret_cast<const uint4*>(&grows[row * 480 + 32 + d]);
      const u16* rp = reinterpret_cast<const u16*>(&rv);
      const u16* gp = reinterpret_cast<const u16*>(&gv);
      uint4 ov;
      u16* op = reinterpret_cast<u16*>(&ov);
#pragma unroll
      for (int i = 0; i < 8; ++i) op[i] = f2bf(bf2f(gp[i]) * bf2f(rp[i]));
      *reinterpret_cast<uint4*>(&grows[row * 480 + 32 + d]) = ov;
    }
  }
  {
    int d = t >> 1;
    int nh = (t & 1) << 5;
    size_t crow = (size_t)b * 160 + 32 + d;
#pragma unroll
    for (int q = 0; q < 4; ++q) {
      int nn = n0 + nh + q * 8;
      uint4 gv = *reinterpret_cast<const uint4*>(&gt0[crow * 4096 + nn]);
      const u16* gp = reinterpret_cast<const u16*>(&gv);
      uint4 ov;
      u16* op = reinterpret_cast<u16*>(&ov);
#pragma unroll
      for (int i = 0; i < 8; ++i) {
        float rv = bf2f(rbuf[((size_t)(nn + i) * 16 + b) * 128 + d]);
        op[i] = f2bf(bf2f(gp[i]) * rv);
      }
      *reinterpret_cast<uint4*>(&gt0[crow * 4096 + nn]) = ov;
    }
  }
}

// ---------------- final: GRU combine + LayerNorm ----------------
__global__ __launch_bounds__(256) void final_kernel(const u16* __restrict__ ht,
                                                    const u16* __restrict__ zbuf,
                                                    const float* __restrict__ h_prev,
                                                    const float* __restrict__ gamma,
                                                    const float* __restrict__ beta,
                                                    float* __restrict__ out) {
  const int lane = threadIdx.x & 63, wid = threadIdx.x >> 6;
  const size_t row = (size_t)blockIdx.x * 4 + wid;  // n*16+b
  const int b = (int)(row & 15), n = (int)(row >> 4);
  const int d0 = lane * 2;
  u32 hv = *reinterpret_cast<const u32*>(&ht[row * 128 + d0]);
  u32 zv = *reinterpret_cast<const u32*>(&zbuf[row * 128 + d0]);
  float2 hp = *reinterpret_cast<const float2*>(&h_prev[((size_t)b * 4096 + n) * 128 + d0]);
  float z0 = bf2f((u16)(zv & 0xFFFF)), z1 = bf2f((u16)(zv >> 16));
  float t0 = bf2f((u16)(hv & 0xFFFF)), t1 = bf2f((u16)(hv >> 16));
  float h0 = (1.f - z0) * hp.x + z0 * t0;
  float h1 = (1.f - z1) * hp.y + z1 * t1;
  float s = h0 + h1, ss = h0 * h0 + h1 * h1;
#pragma unroll
  for (int off = 32; off >= 1; off >>= 1) {
    s += __shfl_xor(s, off);
    ss += __shfl_xor(ss, off);
  }
  float mu = s * (1.f / 128.f);
  float var = ss * (1.f / 128.f) - mu * mu;
  float rstd = rsqrtf(var + 1e-5f);
  float2 gv = *reinterpret_cast<const float2*>(&gamma[d0]);
  float2 bv = *reinterpret_cast<const float2*>(&beta[d0]);
  float o0 = (h0 - mu) * rstd * gv.x + bv.x;
  float o1 = (h1 - mu) * rstd * gv.y + bv.y;
  *reinterpret_cast<float2*>(&out[((size_t)b * 4096 + n) * 128 + d0]) =
      make_float2(o0, o1);
}

extern "C" void kernel_launch(void* const* d_in, const int* in_sizes, int n_in,
                              void* d_out, int out_size, void* d_ws, size_t ws_size,
                              hipStream_t stream) {
  const float* x_t = (const float*)d_in[0];
  const float* h_prev = (const float*)d_in[1];
  const float* adj = (const float*)d_in[2];
  const float* Wz = (const float*)d_in[3];
  const float* bz = (const float*)d_in[4];
  const float* Wr = (const float*)d_in[5];
  const float* br = (const float*)d_in[6];
  const float* Wh = (const float*)d_in[7];
  const float* bh = (const float*)d_in[8];
  const float* gamma = (const float*)d_in[9];
  const float* beta = (const float*)d_in[10];
  float* out = (float*)d_out;

  if (ws_size < (size_t)210083840) return;

  char* ws = (char*)d_ws;
  u16* adjb = (u16*)(ws);                                // 33,554,432 B
  u16* gt0 = (u16*)(ws + 33554432);                      // 2 x 20,971,520 B used
  u16* gt1 = gt0 + (size_t)2560 * 4096;
  u16* grows = (u16*)(ws + 96468992);                    // 62,914,560 B
  u16* zbuf = (u16*)(ws + 159383552);                    // 16,777,216 B
  u16* rbuf = (u16*)(ws + 176160768);                    // 16,777,216 B
  u16* htb = (u16*)(ws + 192937984);                     // 16,777,216 B
  u16* wzr = (u16*)(ws + 209715200);                     // 245,760 B
  u16* whb = (u16*)(ws + 209960960);                     // 122,880 B

  dim3 blk(256);
  cvt_f32_bf16<<<dim3(4096), blk, 0, stream>>>(adj, adjb, 4194304);
  cvt_f32_bf16<<<dim3(60), blk, 0, stream>>>(Wz, wzr, 15360);
  cvt_f32_bf16<<<dim3(60), blk, 0, stream>>>(Wr, wzr + 61440, 15360);
  cvt_f32_bf16<<<dim3(60), blk, 0, stream>>>(Wh, whb, 15360);
  prep_kernel<<<dim3(64, 16), blk, 0, stream>>>(x_t, h_prev, gt0, grows);
  // phase 1 diffusion: hop1 (needs transposed out for hop2), hop2 (rows only)
  gemm_nt<0, 0, 1><<<dim3(32, 20), blk, 0, stream>>>(adjb, 4096, gt0, 4096, 4096,
                                                     gt1, grows + 160, nullptr, nullptr);
  gemm_nt<0, 0, 0><<<dim3(32, 20), blk, 0, stream>>>(adjb, 4096, gt1, 4096, 4096,
                                                     nullptr, grows + 320, nullptr, nullptr);
  // z, r gates
  gemm_nt<1, 0, 1><<<dim3(512, 2), blk, 0, stream>>>(grows, 480, wzr, 480, 480,
                                                     zbuf, rbuf, bz, br);
  // cand: multiply h-features by r (both layouts)
  cand_kernel<<<dim3(64, 16), blk, 0, stream>>>(grows, gt0, rbuf);
  // phase 2 diffusion: h-channels only (x-channels of grows retain phase-1 values)
  gemm_nt<0, 1, 1><<<dim3(32, 16), blk, 0, stream>>>(adjb, 4096, gt0, 4096, 4096,
                                                     gt1, grows + 160, nullptr, nullptr);
  gemm_nt<0, 1, 0><<<dim3(32, 16), blk, 0, stream>>>(adjb, 4096, gt1, 4096, 4096,
                                                     nullptr, grows + 320, nullptr, nullptr);
  // h_tilde
  gemm_nt<2, 0, 1><<<dim3(512, 1), blk, 0, stream>>>(grows, 480, whb, 480, 480,
                                                     htb, nullptr, bh, nullptr);
  final_kernel<<<dim3(16384), blk, 0, stream>>>(htb, zbuf, h_prev, gamma, beta, out);
}